// Round 2
// baseline (7656.178 us; speedup 1.0000x reference)
//
#include <hip/hip_runtime.h>
#include <hip/hip_bf16.h>
#include <stdint.h>

// ---------------------------------------------------------------------------
// GRU over sequence. B=64, T=512, D=1024, H=1024.
//   Precompute: xproj[m][0:2048]   = x@W[:D] + W_b   (m = b*T + t)
//               xproj[m][2048:3072]= x@U[:D] + U_b
//   Sequential: persistent 64 blocks x 512 thr, 2 grid barriers/step.
//     Block owns batch-row group mh = b&3 (16 rows). h fp32 carry in regs.
//     Cross-block data via agent-scope relaxed atomics (sc1 -> LLC).
//   Barrier v4: raw s_barrier + TARGETED waits. __syncthreads lowers to
//     "s_waitcnt vmcnt(0) lgkmcnt(0); s_barrier" which drained out-stores +
//     xproj prefetches 7x/step (the round-1 residual). Now: per-wave
//     vmcnt(0) drain of ONLY the exchange store (out/prefetch issued after),
//     LDS ds_add arrive counter, wave0 polls LDS then flags + 64-lane remote
//     sweep; others join via bare s_barrier. LDS-producer barriers use
//     lgkmcnt(0)-only.
// ---------------------------------------------------------------------------

typedef unsigned short u16;
typedef unsigned long long u64;
typedef __attribute__((ext_vector_type(8))) short bf16x8;
typedef __attribute__((ext_vector_type(4))) float f32x4;

constexpr int Bsz = 64, Tt = 512, Dd = 1024, Hh = 1024;
constexpr int Mrows = Bsz * Tt;   // 32768
constexpr int NP = 3 * Hh;        // 3072
constexpr int NBLK = 64, THR = 512;

// workspace layout (bytes)
constexpr size_t SZ_XPROJ = (size_t)Mrows * NP * 2;   // 201326592
constexpr size_t SZ_XBF   = (size_t)Mrows * Dd * 2;   //  67108864
constexpr size_t SZ_PT    = (size_t)NP * 1024 * 2;    //   6291456
constexpr size_t SZ_WHT   = (size_t)2048 * 1024 * 2;  //   4194304
constexpr size_t SZ_UHT   = (size_t)1024 * 1024 * 2;  //   2097152
constexpr size_t OFF_XPROJ = 0;
constexpr size_t OFF_XBF   = OFF_XPROJ + SZ_XPROJ;
constexpr size_t OFF_PT    = OFF_XBF + SZ_XBF;
constexpr size_t OFF_WHT   = OFF_PT + SZ_PT;
constexpr size_t OFF_UHT   = OFF_WHT + SZ_WHT;
constexpr size_t OFF_HG    = OFF_UHT + SZ_UHT;          // h:  [4][1024][16] u16 = 128KB
constexpr size_t OFF_RHG   = OFF_HG  + 131072;          // rh: [4][1024][16] u16 = 128KB
constexpr size_t OFF_UFP   = OFF_RHG + 131072;          // u:  [64][1024] f32 = 256KB
constexpr size_t OFF_BAR   = OFF_UFP + 262144;          // 64 flags x 64B = 4KB
constexpr size_t WS_NEEDED = OFF_BAR + 4096;

__device__ __forceinline__ float b2f(u16 u) {
  union { unsigned i; float f; } x; x.i = ((unsigned)u) << 16; return x.f;
}
__device__ __forceinline__ u16 f2b(float f) {
  union { float f; unsigned i; } x; x.f = f;
  unsigned r = (x.i >> 16) & 1u;
  return (u16)((x.i + 0x7fffu + r) >> 16);
}
__device__ __forceinline__ float sigmoidf_(float x) { return 1.0f / (1.0f + __expf(-x)); }
__device__ __forceinline__ float tanhf_(float x) { return 1.0f - 2.0f / (__expf(2.0f * x) + 1.0f); }

__device__ __forceinline__ u64 ldA_u64(const u64* p) {
  return __hip_atomic_load(p, __ATOMIC_RELAXED, __HIP_MEMORY_SCOPE_AGENT);
}
__device__ __forceinline__ void stA_u64(u64* p, u64 v) {
  __hip_atomic_store(p, v, __ATOMIC_RELAXED, __HIP_MEMORY_SCOPE_AGENT);
}
__device__ __forceinline__ float ldA_f32(const float* p) {
  return __hip_atomic_load(p, __ATOMIC_RELAXED, __HIP_MEMORY_SCOPE_AGENT);
}
__device__ __forceinline__ void stA_f32(float* p, float v) {
  __hip_atomic_store(p, v, __ATOMIC_RELAXED, __HIP_MEMORY_SCOPE_AGENT);
}
__device__ __forceinline__ unsigned ldA_u32(const unsigned* p) {
  return __hip_atomic_load(p, __ATOMIC_RELAXED, __HIP_MEMORY_SCOPE_AGENT);
}
__device__ __forceinline__ void stA_u32(unsigned* p, unsigned v) {
  __hip_atomic_store(p, v, __ATOMIC_RELAXED, __HIP_MEMORY_SCOPE_AGENT);
}

// targeted sync primitives (asm "memory" clobber = compiler fence)
__device__ __forceinline__ void drain_vm() {            // wait own vmem only
  asm volatile("s_waitcnt vmcnt(0)" ::: "memory");
}
__device__ __forceinline__ void bar_lds() {             // LDS-producer barrier
  asm volatile("s_waitcnt lgkmcnt(0)\n\ts_barrier" ::: "memory");
}
__device__ __forceinline__ void bar_x() {               // plain join, NO drain
  asm volatile("s_barrier" ::: "memory");
}
__device__ __forceinline__ void lds_arrive(unsigned* c) {
  __hip_atomic_fetch_add(c, 1u, __ATOMIC_RELAXED, __HIP_MEMORY_SCOPE_WORKGROUP);
}
__device__ __forceinline__ unsigned lds_peek(unsigned* c) {
  return __hip_atomic_load(c, __ATOMIC_RELAXED, __HIP_MEMORY_SCOPE_WORKGROUP);
}

// async global->LDS, 16B per lane (used by k_gemm only)
__device__ __forceinline__ void gl2lds16(const void* g, void* l) {
  __builtin_amdgcn_global_load_lds(
      (const __attribute__((address_space(1))) void*)g,
      (__attribute__((address_space(3))) void*)l, 16, 0, 0);
}

// ------------------------------- prep kernels ------------------------------
__global__ void k_prep_x(const float* __restrict__ x, u16* __restrict__ xbf,
                         const float* __restrict__ h0, u16* __restrict__ h_g,
                         unsigned* __restrict__ bar) {
  size_t i = (size_t)blockIdx.x * blockDim.x + threadIdx.x;
  size_t stride = (size_t)gridDim.x * blockDim.x;
  if (i < 1024) bar[i] = 0u;   // 64 flag lines (16 u32 each)
  for (size_t k = i; k < (size_t)Mrows * Dd; k += stride) xbf[k] = f2b(x[k]);
  // h_g[g][c][r] = f2b(h0[(g*16+r)*1024 + c])
  for (size_t k = i; k < (size_t)Bsz * Hh; k += stride) {
    int r = (int)(k & 15), c = (int)((k >> 4) & 1023), g = (int)(k >> 14);
    h_g[k] = f2b(h0[(size_t)(g * 16 + r) * 1024 + c]);
  }
}

// coalesced reads: grid (24, 1024), block 256. blockIdx.y = k.
__global__ void k_prep_w(const float* __restrict__ W, const float* __restrict__ U,
                         u16* __restrict__ Pt, u16* __restrict__ Wht, u16* __restrict__ Uht) {
  int k = blockIdx.y, xb = blockIdx.x, tid = threadIdx.x;
  if (xb < 12) {            // Pt[n][k], n 0..3071
    int n = xb * 256 + tid;
    float v = (n < 2048) ? W[(size_t)k * 2048 + n] : U[(size_t)k * 1024 + (n - 2048)];
    Pt[(size_t)n * 1024 + k] = f2b(v);
  } else if (xb < 20) {     // Wht[n][k] = W[1024+k][n], n 0..2047
    int n = (xb - 12) * 256 + tid;
    Wht[(size_t)n * 1024 + k] = f2b(W[(size_t)(1024 + k) * 2048 + n]);
  } else {                  // Uht[n][k] = U[1024+k][n], n 0..1023
    int n = (xb - 20) * 256 + tid;
    Uht[(size_t)n * 1024 + k] = f2b(U[(size_t)(1024 + k) * 1024 + n]);
  }
}

__global__ void k_ws_too_small(float* out) {
  out[threadIdx.x] = 12345.0f;  // sentinel: ws_size < WS_NEEDED
}

// --------------------------- precompute GEMM (m97) -------------------------
__global__ void k_gemm(const u16* __restrict__ xbf, const u16* __restrict__ Pt,
                       const float* __restrict__ Wb, const float* __restrict__ Ub,
                       u16* __restrict__ xproj) {
  __shared__ u16 As[128 * 32];
  __shared__ u16 Bs[128 * 32];
  const int tid = threadIdx.x, lane = tid & 63, w = tid >> 6;
  const int l15 = lane & 15, q = lane >> 4;
  const int bm = blockIdx.x, bn = blockIdx.y;
  const int wm = w >> 1, wn = w & 1;
  const int lr = lane >> 2;
  const int lc = (lane & 3) * 8;
  f32x4 acc[4][4] = {};
  for (int kt = 0; kt < 32; ++kt) {
    __syncthreads();
    {
      const u16* ga = xbf + (size_t)(bm * 128 + w * 32 + lr) * 1024 + kt * 32 + lc;
      gl2lds16(ga, As + w * 1024);
      gl2lds16(ga + 16 * 1024, As + w * 1024 + 512);
      const u16* gb = Pt + (size_t)(bn * 128 + w * 32 + lr) * 1024 + kt * 32 + lc;
      gl2lds16(gb, Bs + w * 1024);
      gl2lds16(gb + 16 * 1024, Bs + w * 1024 + 512);
    }
    __syncthreads();
    bf16x8 af[4], bfr[4];
#pragma unroll
    for (int i = 0; i < 4; ++i)
      af[i] = *(const bf16x8*)(As + (wm * 64 + i * 16 + l15) * 32 + q * 8);
#pragma unroll
    for (int j = 0; j < 4; ++j)
      bfr[j] = *(const bf16x8*)(Bs + (wn * 64 + j * 16 + l15) * 32 + q * 8);
#pragma unroll
    for (int i = 0; i < 4; ++i)
#pragma unroll
      for (int j = 0; j < 4; ++j)
        acc[i][j] = __builtin_amdgcn_mfma_f32_16x16x32_bf16(af[i], bfr[j], acc[i][j], 0, 0, 0);
  }
#pragma unroll
  for (int j = 0; j < 4; ++j) {
    int n = bn * 128 + wn * 64 + j * 16 + l15;
    float bias = (n < 2048) ? Wb[n] : Ub[n - 2048];
#pragma unroll
    for (int i = 0; i < 4; ++i) {
#pragma unroll
      for (int r = 0; r < 4; ++r) {
        int m = bm * 128 + wm * 64 + i * 16 + q * 4 + r;
        xproj[(size_t)m * NP + n] = f2b(acc[i][j][r] + bias);
      }
    }
  }
}

// ------------------------------ sequential scan ----------------------------
// 64 blocks x 512 thr (8 waves). Block owns 16 batch rows (mh = b&3).
// Phase A: wave w -> gi col-tile a_nt=(b>>2)*8+w (0..127), K=1024, 2 acc chains.
// Phase B: wave pair -> c col-tile b_nt=(b>>2)*4+(w>>1) (0..63), K split by w&1.
__global__ void __launch_bounds__(THR, 2)
k_seq(const u16* __restrict__ xproj, const u16* __restrict__ Wht,
      const u16* __restrict__ Uht, const float* __restrict__ h0,
      u16* __restrict__ h_g, u16* __restrict__ rh_g, float* __restrict__ u_fp,
      float* __restrict__ out, unsigned* __restrict__ bar) {
  __shared__ u16 hs[16 * 1032];      // staged h or rh, row-major, pad 8
  __shared__ f32x4 red[4][64];       // phase-B split-K reduction
  __shared__ unsigned acnt;          // per-block arrive counter (monotonic)
  const int tid = threadIdx.x, lane = tid & 63, w = tid >> 6;
  const int l15 = lane & 15, q = lane >> 4;
  const int b = blockIdx.x;
  const int mh = b & 3;              // 16-row batch group
  const int rbase = mh * 16;
  const int a_nt = (b >> 2) * 8 + w;         // 0..127
  const int a_col = a_nt * 16 + l15;         // 0..2047
  const int b_nt = (b >> 2) * 4 + (w >> 1);  // 0..63
  const int b_kh = w & 1;
  const int b_col = b_nt * 16 + l15;         // 0..1023

  // ---- recurrent weights -> registers for the whole scan ----
  bf16x8 wa[32];
  { const u16* p = Wht + (size_t)a_col * 1024 + q * 8;
#pragma unroll
    for (int s = 0; s < 32; ++s) wa[s] = *(const bf16x8*)(p + s * 32); }
  bf16x8 wb[16];
  { const u16* p = Uht + (size_t)b_col * 1024 + b_kh * 512 + q * 8;
#pragma unroll
    for (int s = 0; s < 16; ++s) wb[s] = *(const bf16x8*)(p + s * 32); }

  // fp32 hidden-state carry: wave with b_kh==0 owns rows rbase+q*4+r, col b_col
  float hp[4];
#pragma unroll
  for (int r = 0; r < 4; ++r) hp[r] = h0[(size_t)(rbase + q * 4 + r) * 1024 + b_col];

  // prefetch gx (phase A) and ux (phase B) for t=0
  float gxp[4];
#pragma unroll
  for (int r = 0; r < 4; ++r)
    gxp[r] = b2f(xproj[(size_t)((rbase + q * 4 + r) * Tt + 0) * NP + a_col]);
  float uxp[4] = {0.f, 0.f, 0.f, 0.f};
  if (b_kh == 0) {
#pragma unroll
    for (int r = 0; r < 4; ++r)
      uxp[r] = b2f(xproj[(size_t)((rbase + q * 4 + r) * Tt + 0) * NP + 2048 + b_col]);
  }

  const u64* hg64 = (const u64*)h_g + mh * 4096;    // [1024 col][4 u64]
  const u64* rg64 = (const u64*)rh_g + mh * 4096;

  if (tid == 0) acnt = 0;
  __syncthreads();   // one-time init (full drain OK here)

  unsigned bct = 0;      // flag ordinal (per half-step)
  unsigned atgt = 0;     // LDS arrive target
#pragma unroll 1
  for (int t = 0; t < Tt; ++t) {
    // ---- stage h (group mh) into LDS: 32KB contiguous, sc1 loads ----
#pragma unroll
    for (int j = 0; j < 8; ++j) {
      int f = j * THR + tid;               // 0..4095
      u64 v = ldA_u64(hg64 + f);
      int col = f >> 2, rr = f & 3;        // rows rr*4..+3
      u16* d = hs + rr * 4 * 1032 + col;
      d[0] = (u16)v; d[1032] = (u16)(v >> 16);
      d[2064] = (u16)(v >> 32); d[3096] = (u16)(v >> 48);
    }
    bar_lds();   // ds_writes visible block-wide; out/prefetch NOT drained

    // ---- phase A: gi tile = h @ Wh[:,a_col tile], K=1024, 2 acc chains ----
    f32x4 acc = {0.f, 0.f, 0.f, 0.f}, acc2 = {0.f, 0.f, 0.f, 0.f};
    {
      const u16* hb = hs + l15 * 1032 + q * 8;
#pragma unroll
      for (int s = 0; s < 32; s += 2) {
        bf16x8 a0 = *(const bf16x8*)(hb + s * 32);
        bf16x8 a1 = *(const bf16x8*)(hb + (s + 1) * 32);
        acc  = __builtin_amdgcn_mfma_f32_16x16x32_bf16(a0, wa[s], acc, 0, 0, 0);
        acc2 = __builtin_amdgcn_mfma_f32_16x16x32_bf16(a1, wa[s + 1], acc2, 0, 0, 0);
      }
      acc += acc2;
    }
    if (a_nt < 64) {   // r-columns: rh = sigmoid(gi)*h  (bf16, packed u64)
      u64 pk = 0;
#pragma unroll
      for (int r = 0; r < 4; ++r) {
        int lrow = q * 4 + r;
        float g = sigmoidf_(acc[r] + gxp[r]);
        float hcell = b2f(hs[lrow * 1032 + a_col]);
        pk |= (u64)f2b(g * hcell) << (16 * r);
      }
      stA_u64((u64*)rh_g + mh * 4096 + a_col * 4 + q, pk);
    } else {           // u-columns: fp32
#pragma unroll
      for (int r = 0; r < 4; ++r) {
        int lrow = q * 4 + r;
        stA_f32(&u_fp[(size_t)(rbase + lrow) * 1024 + (a_col - 1024)],
                sigmoidf_(acc[r] + gxp[r]));
      }
    }
    // ---- exchange barrier 1: drain ONLY exchange stores, arrive, poll ----
    drain_vm();
    if (lane == 0) lds_arrive(&acnt);
    atgt += 8; ++bct;
    if (w == 0) {
      while (lds_peek(&acnt) < atgt) {}
      if (lane == 0) stA_u32(bar + (b << 4), bct);
      while (__ballot(ldA_u32(bar + (lane << 4)) < bct) != 0ull) {}
    }
    bar_x();

    // ---- hoist u (LLC) loads: overlap with rh staging + phase-B MFMA ----
    float uvr[4] = {0.f, 0.f, 0.f, 0.f};
    if (b_kh == 0) {
#pragma unroll
      for (int r = 0; r < 4; ++r)
        uvr[r] = ldA_f32(&u_fp[(size_t)(rbase + q * 4 + r) * 1024 + b_col]);
    }

    // ---- stage rh (group mh) into LDS ----
#pragma unroll
    for (int j = 0; j < 8; ++j) {
      int f = j * THR + tid;
      u64 v = ldA_u64(rg64 + f);
      int col = f >> 2, rr = f & 3;
      u16* d = hs + rr * 4 * 1032 + col;
      d[0] = (u16)v; d[1032] = (u16)(v >> 16);
      d[2064] = (u16)(v >> 32); d[3096] = (u16)(v >> 48);
    }
    bar_lds();

    // ---- phase B: c tile = rh @ Uh[:,b_col tile], K split 2, 2 acc chains ----
    f32x4 accb = {0.f, 0.f, 0.f, 0.f}, accb2 = {0.f, 0.f, 0.f, 0.f};
    {
      const u16* rb = hs + l15 * 1032 + b_kh * 512 + q * 8;
#pragma unroll
      for (int s = 0; s < 16; s += 2) {
        bf16x8 a0 = *(const bf16x8*)(rb + s * 32);
        bf16x8 a1 = *(const bf16x8*)(rb + (s + 1) * 32);
        accb  = __builtin_amdgcn_mfma_f32_16x16x32_bf16(a0, wb[s], accb, 0, 0, 0);
        accb2 = __builtin_amdgcn_mfma_f32_16x16x32_bf16(a1, wb[s + 1], accb2, 0, 0, 0);
      }
      accb += accb2;
    }
    if (b_kh == 1) red[w >> 1][lane] = accb;
    bar_lds();   // red visible; no vmcnt drain
    float hn_[4];
    if (b_kh == 0) {
      accb += red[w >> 1][lane];
      u64 pk = 0;
#pragma unroll
      for (int r = 0; r < 4; ++r) {
        float c = tanhf_(accb[r] + uxp[r]);
        float hn = uvr[r] * hp[r] + (1.0f - uvr[r]) * c;
        hp[r] = hn; hn_[r] = hn;
        pk |= (u64)f2b(hn) << (16 * r);
      }
      stA_u64((u64*)h_g + mh * 4096 + b_col * 4 + q, pk);
    }
    // ---- exchange barrier 2: drain h store FIRST, then fire out+prefetch ----
    drain_vm();
    if (lane == 0) lds_arrive(&acnt);
    atgt += 8; ++bct;
    if (b_kh == 0) {   // out stores: after drain -> never on barrier path
#pragma unroll
      for (int r = 0; r < 4; ++r)
        out[((size_t)(rbase + q * 4 + r) * Tt + t) * 1024 + b_col] = hn_[r];
    }
    if (t + 1 < Tt) {  // prefetch next gx/ux (read-only, plain cached)
#pragma unroll
      for (int r = 0; r < 4; ++r)
        gxp[r] = b2f(xproj[(size_t)((rbase + q * 4 + r) * Tt + (t + 1)) * NP + a_col]);
      if (b_kh == 0) {
#pragma unroll
        for (int r = 0; r < 4; ++r)
          uxp[r] = b2f(xproj[(size_t)((rbase + q * 4 + r) * Tt + (t + 1)) * NP + 2048 + b_col]);
      }
      if (w == 0) {
        while (lds_peek(&acnt) < atgt) {}
        if (lane == 0) stA_u32(bar + (b << 4), bct);
        while (__ballot(ldA_u32(bar + (lane << 4)) < bct) != 0ull) {}
      }
      bar_x();
    }
    // last step: no barrier needed, kernel ends (out stores flushed at exit)
  }
}

// --------------------------------- launch ----------------------------------
extern "C" void kernel_launch(void* const* d_in, const int* in_sizes, int n_in,
                              void* d_out, int out_size, void* d_ws, size_t ws_size,
                              hipStream_t stream) {
  const float* x  = (const float*)d_in[0];
  const float* h0 = (const float*)d_in[1];
  const float* W  = (const float*)d_in[2];
  const float* Wb = (const float*)d_in[3];
  const float* U  = (const float*)d_in[4];
  const float* Ub = (const float*)d_in[5];
  float* out = (float*)d_out;

  if (ws_size < WS_NEEDED) {
    k_ws_too_small<<<1, 256, 0, stream>>>(out);
    return;
  }

  char* ws = (char*)d_ws;
  u16* xproj = (u16*)(ws + OFF_XPROJ);
  u16* xbf   = (u16*)(ws + OFF_XBF);
  u16* Pt    = (u16*)(ws + OFF_PT);
  u16* Wht   = (u16*)(ws + OFF_WHT);
  u16* Uht   = (u16*)(ws + OFF_UHT);
  u16* h_g   = (u16*)(ws + OFF_HG);
  u16* rh_g  = (u16*)(ws + OFF_RHG);
  float* u_fp = (float*)(ws + OFF_UFP);
  unsigned* bar = (unsigned*)(ws + OFF_BAR);

  k_prep_x<<<2048, 256, 0, stream>>>(x, xbf, h0, h_g, bar);
  k_prep_w<<<dim3(24, 1024), 256, 0, stream>>>(W, U, Pt, Wht, Uht);
  k_gemm<<<dim3(256, 24), 256, 0, stream>>>(xbf, Pt, Wb, Ub, xproj);
  k_seq<<<NBLK, 512, 0, stream>>>(xproj, Wht, Uht, h0, h_g, rh_g, u_fp, out, bar);
}

// Round 3
// 4869.678 us; speedup vs baseline: 1.5722x; 1.5722x over previous
//
#include <hip/hip_runtime.h>
#include <hip/hip_bf16.h>
#include <stdint.h>

// ---------------------------------------------------------------------------
// GRU over sequence. B=64, T=512, D=1024, H=1024.
//   Precompute: xproj[m][0:2048]   = x@W[:D] + W_b   (m = b*T + t)
//               xproj[m][2048:3072]= x@U[:D] + U_b
//   Sequential: persistent 64 blocks x 512 thr. The 4 batch-row groups
//   (mh = b&3, 16 rows each) are INDEPENDENT chains: 16-block group-local
//   barriers (v5), not grid-wide.
//   v5 changes vs v4:
//     - u-gate never exchanged: even waves' phase-A u-tile == their phase-B
//       c-tile, so u = sigmoid(acc+gx) stays in registers (u_fp deleted).
//     - staging: 4x u64 LLC loads + register transpose-pack + 4x ds_write_b64
//       per iteration (was 1 load + 4 scattered ds_write_b16: 4-way conflicts).
//     - flag sweep polls only the 16 group blocks.
// ---------------------------------------------------------------------------

typedef unsigned short u16;
typedef unsigned long long u64;
typedef __attribute__((ext_vector_type(8))) short bf16x8;
typedef __attribute__((ext_vector_type(4))) float f32x4;

constexpr int Bsz = 64, Tt = 512, Dd = 1024, Hh = 1024;
constexpr int Mrows = Bsz * Tt;   // 32768
constexpr int NP = 3 * Hh;        // 3072
constexpr int NBLK = 64, THR = 512;

// workspace layout (bytes)
constexpr size_t SZ_XPROJ = (size_t)Mrows * NP * 2;   // 201326592
constexpr size_t SZ_XBF   = (size_t)Mrows * Dd * 2;   //  67108864
constexpr size_t SZ_PT    = (size_t)NP * 1024 * 2;    //   6291456
constexpr size_t SZ_WHT   = (size_t)2048 * 1024 * 2;  //   4194304
constexpr size_t SZ_UHT   = (size_t)1024 * 1024 * 2;  //   2097152
constexpr size_t OFF_XPROJ = 0;
constexpr size_t OFF_XBF   = OFF_XPROJ + SZ_XPROJ;
constexpr size_t OFF_PT    = OFF_XBF + SZ_XBF;
constexpr size_t OFF_WHT   = OFF_PT + SZ_PT;
constexpr size_t OFF_UHT   = OFF_WHT + SZ_WHT;
constexpr size_t OFF_HG    = OFF_UHT + SZ_UHT;          // h:  [4][1024][16] u16 = 128KB
constexpr size_t OFF_RHG   = OFF_HG  + 131072;          // rh: [4][1024][16] u16 = 128KB
constexpr size_t OFF_BAR   = OFF_RHG + 131072;          // 64 flags x 64B = 4KB
constexpr size_t WS_NEEDED = OFF_BAR + 4096;

__device__ __forceinline__ float b2f(u16 u) {
  union { unsigned i; float f; } x; x.i = ((unsigned)u) << 16; return x.f;
}
__device__ __forceinline__ u16 f2b(float f) {
  union { float f; unsigned i; } x; x.f = f;
  unsigned r = (x.i >> 16) & 1u;
  return (u16)((x.i + 0x7fffu + r) >> 16);
}
__device__ __forceinline__ float sigmoidf_(float x) { return 1.0f / (1.0f + __expf(-x)); }
__device__ __forceinline__ float tanhf_(float x) { return 1.0f - 2.0f / (__expf(2.0f * x) + 1.0f); }

__device__ __forceinline__ u64 ldA_u64(const u64* p) {
  return __hip_atomic_load(p, __ATOMIC_RELAXED, __HIP_MEMORY_SCOPE_AGENT);
}
__device__ __forceinline__ void stA_u64(u64* p, u64 v) {
  __hip_atomic_store(p, v, __ATOMIC_RELAXED, __HIP_MEMORY_SCOPE_AGENT);
}
__device__ __forceinline__ unsigned ldA_u32(const unsigned* p) {
  return __hip_atomic_load(p, __ATOMIC_RELAXED, __HIP_MEMORY_SCOPE_AGENT);
}
__device__ __forceinline__ void stA_u32(unsigned* p, unsigned v) {
  __hip_atomic_store(p, v, __ATOMIC_RELAXED, __HIP_MEMORY_SCOPE_AGENT);
}

// targeted sync primitives (asm "memory" clobber = compiler fence)
__device__ __forceinline__ void drain_vm() {            // wait own vmem only
  asm volatile("s_waitcnt vmcnt(0)" ::: "memory");
}
__device__ __forceinline__ void bar_lds() {             // LDS-producer barrier
  asm volatile("s_waitcnt lgkmcnt(0)\n\ts_barrier" ::: "memory");
}
__device__ __forceinline__ void bar_x() {               // plain join, NO drain
  asm volatile("s_barrier" ::: "memory");
}
__device__ __forceinline__ void lds_arrive(unsigned* c) {
  __hip_atomic_fetch_add(c, 1u, __ATOMIC_RELAXED, __HIP_MEMORY_SCOPE_WORKGROUP);
}
__device__ __forceinline__ unsigned lds_peek(unsigned* c) {
  return __hip_atomic_load(c, __ATOMIC_RELAXED, __HIP_MEMORY_SCOPE_WORKGROUP);
}

// async global->LDS, 16B per lane (used by k_gemm only)
__device__ __forceinline__ void gl2lds16(const void* g, void* l) {
  __builtin_amdgcn_global_load_lds(
      (const __attribute__((address_space(1))) void*)g,
      (__attribute__((address_space(3))) void*)l, 16, 0, 0);
}

// ------------------------------- prep kernels ------------------------------
__global__ void k_prep_x(const float* __restrict__ x, u16* __restrict__ xbf,
                         const float* __restrict__ h0, u16* __restrict__ h_g,
                         unsigned* __restrict__ bar) {
  size_t i = (size_t)blockIdx.x * blockDim.x + threadIdx.x;
  size_t stride = (size_t)gridDim.x * blockDim.x;
  if (i < 1024) bar[i] = 0u;   // 64 flag lines (16 u32 each)
  for (size_t k = i; k < (size_t)Mrows * Dd; k += stride) xbf[k] = f2b(x[k]);
  // h_g[g][c][r] = f2b(h0[(g*16+r)*1024 + c])
  for (size_t k = i; k < (size_t)Bsz * Hh; k += stride) {
    int r = (int)(k & 15), c = (int)((k >> 4) & 1023), g = (int)(k >> 14);
    h_g[k] = f2b(h0[(size_t)(g * 16 + r) * 1024 + c]);
  }
}

// coalesced reads: grid (24, 1024), block 256. blockIdx.y = k.
__global__ void k_prep_w(const float* __restrict__ W, const float* __restrict__ U,
                         u16* __restrict__ Pt, u16* __restrict__ Wht, u16* __restrict__ Uht) {
  int k = blockIdx.y, xb = blockIdx.x, tid = threadIdx.x;
  if (xb < 12) {            // Pt[n][k], n 0..3071
    int n = xb * 256 + tid;
    float v = (n < 2048) ? W[(size_t)k * 2048 + n] : U[(size_t)k * 1024 + (n - 2048)];
    Pt[(size_t)n * 1024 + k] = f2b(v);
  } else if (xb < 20) {     // Wht[n][k] = W[1024+k][n], n 0..2047
    int n = (xb - 12) * 256 + tid;
    Wht[(size_t)n * 1024 + k] = f2b(W[(size_t)(1024 + k) * 2048 + n]);
  } else {                  // Uht[n][k] = U[1024+k][n], n 0..1023
    int n = (xb - 20) * 256 + tid;
    Uht[(size_t)n * 1024 + k] = f2b(U[(size_t)(1024 + k) * 1024 + n]);
  }
}

__global__ void k_ws_too_small(float* out) {
  out[threadIdx.x] = 12345.0f;  // sentinel: ws_size < WS_NEEDED
}

// --------------------------- precompute GEMM (m97) -------------------------
__global__ void k_gemm(const u16* __restrict__ xbf, const u16* __restrict__ Pt,
                       const float* __restrict__ Wb, const float* __restrict__ Ub,
                       u16* __restrict__ xproj) {
  __shared__ u16 As[128 * 32];
  __shared__ u16 Bs[128 * 32];
  const int tid = threadIdx.x, lane = tid & 63, w = tid >> 6;
  const int l15 = lane & 15, q = lane >> 4;
  const int bm = blockIdx.x, bn = blockIdx.y;
  const int wm = w >> 1, wn = w & 1;
  const int lr = lane >> 2;
  const int lc = (lane & 3) * 8;
  f32x4 acc[4][4] = {};
  for (int kt = 0; kt < 32; ++kt) {
    __syncthreads();
    {
      const u16* ga = xbf + (size_t)(bm * 128 + w * 32 + lr) * 1024 + kt * 32 + lc;
      gl2lds16(ga, As + w * 1024);
      gl2lds16(ga + 16 * 1024, As + w * 1024 + 512);
      const u16* gb = Pt + (size_t)(bn * 128 + w * 32 + lr) * 1024 + kt * 32 + lc;
      gl2lds16(gb, Bs + w * 1024);
      gl2lds16(gb + 16 * 1024, Bs + w * 1024 + 512);
    }
    __syncthreads();
    bf16x8 af[4], bfr[4];
#pragma unroll
    for (int i = 0; i < 4; ++i)
      af[i] = *(const bf16x8*)(As + (wm * 64 + i * 16 + l15) * 32 + q * 8);
#pragma unroll
    for (int j = 0; j < 4; ++j)
      bfr[j] = *(const bf16x8*)(Bs + (wn * 64 + j * 16 + l15) * 32 + q * 8);
#pragma unroll
    for (int i = 0; i < 4; ++i)
#pragma unroll
      for (int j = 0; j < 4; ++j)
        acc[i][j] = __builtin_amdgcn_mfma_f32_16x16x32_bf16(af[i], bfr[j], acc[i][j], 0, 0, 0);
  }
#pragma unroll
  for (int j = 0; j < 4; ++j) {
    int n = bn * 128 + wn * 64 + j * 16 + l15;
    float bias = (n < 2048) ? Wb[n] : Ub[n - 2048];
#pragma unroll
    for (int i = 0; i < 4; ++i) {
#pragma unroll
      for (int r = 0; r < 4; ++r) {
        int m = bm * 128 + wm * 64 + i * 16 + q * 4 + r;
        xproj[(size_t)m * NP + n] = f2b(acc[i][j][r] + bias);
      }
    }
  }
}

// ---------------------- group-tile staging (v5) ----------------------------
// Source layout: [1024 col][16 row] u16 (u64 = rows 4q..4q+3 of one col).
// Dest: hs row-major [16][1032]. Per thread: 2 x {4 u64 loads, reg transpose,
// 4 ds_write_b64 of 4 adjacent cols}.
__device__ __forceinline__ void stage_tile(const u64* g64, u16* hs, int tid) {
#pragma unroll
  for (int i = 0; i < 2; ++i) {
    int z = i * THR + tid;            // 0..1023
    int rr = z & 3, cq = z >> 2;      // row-quad, col-quad (0..255)
    const u64* p = g64 + cq * 16 + rr;
    u64 v0 = ldA_u64(p);
    u64 v1 = ldA_u64(p + 4);
    u64 v2 = ldA_u64(p + 8);
    u64 v3 = ldA_u64(p + 12);
#pragma unroll
    for (int k = 0; k < 4; ++k) {
      int r = rr * 4 + k;
      u64 wv = (u64)(u16)(v0 >> (16 * k))
             | ((u64)(u16)(v1 >> (16 * k)) << 16)
             | ((u64)(u16)(v2 >> (16 * k)) << 32)
             | ((u64)(u16)(v3 >> (16 * k)) << 48);
      *(u64*)(hs + r * 1032 + cq * 4) = wv;
    }
  }
}

// ------------------------------ sequential scan ----------------------------
// 64 blocks x 512 thr (8 waves). Block owns 16 batch rows (mh = b&3).
// Odd waves:  phase-A r-tile a_nt = bq*4+half (cols 0..1023) -> rh exchange;
//             phase-B K-half 1 partial.
// Even waves: phase-A u-tile a_nt = 64+bq*4+half == phase-B tile (u in regs);
//             phase-B K-half 0 + finish + h exchange.
__global__ void __launch_bounds__(THR, 2)
k_seq(const u16* __restrict__ xproj, const u16* __restrict__ Wht,
      const u16* __restrict__ Uht, const float* __restrict__ h0,
      u16* __restrict__ h_g, u16* __restrict__ rh_g,
      float* __restrict__ out, unsigned* __restrict__ bar) {
  __shared__ u16 hs[16 * 1032];      // staged h or rh, row-major, pad 8
  __shared__ f32x4 red[4][64];       // phase-B split-K reduction
  __shared__ unsigned acnt;          // per-block arrive counter (monotonic)
  const int tid = threadIdx.x, lane = tid & 63, w = tid >> 6;
  const int l15 = lane & 15, q = lane >> 4;
  const int b = blockIdx.x;
  const int mh = b & 3;              // 16-row batch group (independent chain)
  const int rbase = mh * 16;
  const int bq = b >> 2;             // 0..15 (position within group)
  const int half = w >> 1;           // 0..3
  const int odd = w & 1;             // phase-B K-half; phase-A r(1)/u(0) role
  const int a_nt = odd ? (bq * 4 + half) : (64 + bq * 4 + half);
  const int a_col = a_nt * 16 + l15;         // odd: 0..1023, even: 1024..2047
  const int b_col = (bq * 4 + half) * 16 + l15;  // 0..1023

  // ---- recurrent weights -> registers for the whole scan ----
  bf16x8 wa[32];
  { const u16* p = Wht + (size_t)a_col * 1024 + q * 8;
#pragma unroll
    for (int s = 0; s < 32; ++s) wa[s] = *(const bf16x8*)(p + s * 32); }
  bf16x8 wb[16];
  { const u16* p = Uht + (size_t)b_col * 1024 + odd * 512 + q * 8;
#pragma unroll
    for (int s = 0; s < 16; ++s) wb[s] = *(const bf16x8*)(p + s * 32); }

  // fp32 hidden-state carry: even waves own rows rbase+q*4+r, col b_col
  float hp[4];
#pragma unroll
  for (int r = 0; r < 4; ++r) hp[r] = h0[(size_t)(rbase + q * 4 + r) * 1024 + b_col];

  // prefetch gx (phase A) and ux (phase B, even only) for t=0
  float gxp[4];
#pragma unroll
  for (int r = 0; r < 4; ++r)
    gxp[r] = b2f(xproj[(size_t)((rbase + q * 4 + r) * Tt + 0) * NP + a_col]);
  float uxp[4] = {0.f, 0.f, 0.f, 0.f};
  if (!odd) {
#pragma unroll
    for (int r = 0; r < 4; ++r)
      uxp[r] = b2f(xproj[(size_t)((rbase + q * 4 + r) * Tt + 0) * NP + 2048 + b_col]);
  }

  const u64* hg64 = (const u64*)h_g + mh * 4096;    // [1024 col][4 u64]
  const u64* rg64 = (const u64*)rh_g + mh * 4096;
  const int swb = mh + 4 * l15;      // group flag sweep: 16 blocks, 4x redundant

  if (tid == 0) acnt = 0;
  __syncthreads();   // one-time init

  unsigned bct = 0;      // flag ordinal (per half-step)
  unsigned atgt = 0;     // LDS arrive target
#pragma unroll 1
  for (int t = 0; t < Tt; ++t) {
    // ---- stage h (group mh) into LDS ----
    stage_tile(hg64, hs, tid);
    bar_lds();   // ds_writes visible block-wide; nothing else drained

    // ---- phase A: gi tile = h @ Wh[:,a_col tile], K=1024, 2 acc chains ----
    f32x4 acc = {0.f, 0.f, 0.f, 0.f}, acc2 = {0.f, 0.f, 0.f, 0.f};
    {
      const u16* hb = hs + l15 * 1032 + q * 8;
#pragma unroll
      for (int s = 0; s < 32; s += 2) {
        bf16x8 a0 = *(const bf16x8*)(hb + s * 32);
        bf16x8 a1 = *(const bf16x8*)(hb + (s + 1) * 32);
        acc  = __builtin_amdgcn_mfma_f32_16x16x32_bf16(a0, wa[s], acc, 0, 0, 0);
        acc2 = __builtin_amdgcn_mfma_f32_16x16x32_bf16(a1, wa[s + 1], acc2, 0, 0, 0);
      }
      acc += acc2;
    }
    float uvr[4];
    if (odd) {         // r-columns: rh = sigmoid(gi)*h  (bf16, packed u64)
      u64 pk = 0;
#pragma unroll
      for (int r = 0; r < 4; ++r) {
        int lrow = q * 4 + r;
        float g = sigmoidf_(acc[r] + gxp[r]);
        float hcell = b2f(hs[lrow * 1032 + a_col]);
        pk |= (u64)f2b(g * hcell) << (16 * r);
      }
      stA_u64((u64*)rh_g + mh * 4096 + a_col * 4 + q, pk);
    } else {           // u-columns: SAME tile as phase B -> stays in regs
#pragma unroll
      for (int r = 0; r < 4; ++r) uvr[r] = sigmoidf_(acc[r] + gxp[r]);
    }
    // ---- exchange barrier 1 (group-local): drain rh stores, arrive, poll ----
    drain_vm();
    if (lane == 0) lds_arrive(&acnt);
    atgt += 8; ++bct;
    if (w == 0) {
      while (lds_peek(&acnt) < atgt) {}
      if (lane == 0) stA_u32(bar + (b << 4), bct);
      while (__ballot(ldA_u32(bar + (swb << 4)) < bct) != 0ull) {}
    }
    bar_x();

    // ---- stage rh (group mh) into LDS ----
    stage_tile(rg64, hs, tid);
    bar_lds();

    // ---- phase B: c tile = rh @ Uh[:,b_col tile], K split 2, 2 acc chains ----
    f32x4 accb = {0.f, 0.f, 0.f, 0.f}, accb2 = {0.f, 0.f, 0.f, 0.f};
    {
      const u16* rb = hs + l15 * 1032 + odd * 512 + q * 8;
#pragma unroll
      for (int s = 0; s < 16; s += 2) {
        bf16x8 a0 = *(const bf16x8*)(rb + s * 32);
        bf16x8 a1 = *(const bf16x8*)(rb + (s + 1) * 32);
        accb  = __builtin_amdgcn_mfma_f32_16x16x32_bf16(a0, wb[s], accb, 0, 0, 0);
        accb2 = __builtin_amdgcn_mfma_f32_16x16x32_bf16(a1, wb[s + 1], accb2, 0, 0, 0);
      }
      accb += accb2;
    }
    if (odd) red[half][lane] = accb;
    bar_lds();   // red visible; no vmcnt drain
    float hn_[4];
    if (!odd) {
      accb += red[half][lane];
      u64 pk = 0;
#pragma unroll
      for (int r = 0; r < 4; ++r) {
        float c = tanhf_(accb[r] + uxp[r]);
        float hn = uvr[r] * hp[r] + (1.0f - uvr[r]) * c;
        hp[r] = hn; hn_[r] = hn;
        pk |= (u64)f2b(hn) << (16 * r);
      }
      stA_u64((u64*)h_g + mh * 4096 + b_col * 4 + q, pk);
    }
    // ---- exchange barrier 2 (group-local): drain h store, then out+prefetch
    drain_vm();
    if (lane == 0) lds_arrive(&acnt);
    atgt += 8; ++bct;
    if (!odd) {        // out stores: after drain -> never on barrier path
#pragma unroll
      for (int r = 0; r < 4; ++r)
        out[((size_t)(rbase + q * 4 + r) * Tt + t) * 1024 + b_col] = hn_[r];
    }
    if (t + 1 < Tt) {  // prefetch next gx/ux (read-only, plain cached)
#pragma unroll
      for (int r = 0; r < 4; ++r)
        gxp[r] = b2f(xproj[(size_t)((rbase + q * 4 + r) * Tt + (t + 1)) * NP + a_col]);
      if (!odd) {
#pragma unroll
        for (int r = 0; r < 4; ++r)
          uxp[r] = b2f(xproj[(size_t)((rbase + q * 4 + r) * Tt + (t + 1)) * NP + 2048 + b_col]);
      }
      if (w == 0) {
        while (lds_peek(&acnt) < atgt) {}
        if (lane == 0) stA_u32(bar + (b << 4), bct);
        while (__ballot(ldA_u32(bar + (swb << 4)) < bct) != 0ull) {}
      }
      bar_x();
    }
    // last step: no barrier needed, kernel ends (out stores flushed at exit)
  }
}

// --------------------------------- launch ----------------------------------
extern "C" void kernel_launch(void* const* d_in, const int* in_sizes, int n_in,
                              void* d_out, int out_size, void* d_ws, size_t ws_size,
                              hipStream_t stream) {
  const float* x  = (const float*)d_in[0];
  const float* h0 = (const float*)d_in[1];
  const float* W  = (const float*)d_in[2];
  const float* Wb = (const float*)d_in[3];
  const float* U  = (const float*)d_in[4];
  const float* Ub = (const float*)d_in[5];
  float* out = (float*)d_out;

  if (ws_size < WS_NEEDED) {
    k_ws_too_small<<<1, 256, 0, stream>>>(out);
    return;
  }

  char* ws = (char*)d_ws;
  u16* xproj = (u16*)(ws + OFF_XPROJ);
  u16* xbf   = (u16*)(ws + OFF_XBF);
  u16* Pt    = (u16*)(ws + OFF_PT);
  u16* Wht   = (u16*)(ws + OFF_WHT);
  u16* Uht   = (u16*)(ws + OFF_UHT);
  u16* h_g   = (u16*)(ws + OFF_HG);
  u16* rh_g  = (u16*)(ws + OFF_RHG);
  unsigned* bar = (unsigned*)(ws + OFF_BAR);

  k_prep_x<<<2048, 256, 0, stream>>>(x, xbf, h0, h_g, bar);
  k_prep_w<<<dim3(24, 1024), 256, 0, stream>>>(W, U, Pt, Wht, Uht);
  k_gemm<<<dim3(256, 24), 256, 0, stream>>>(xbf, Pt, Wb, Ub, xproj);
  k_seq<<<NBLK, 512, 0, stream>>>(xproj, Wht, Uht, h0, h_g, rh_g, out, bar);
}